// Round 25
// baseline (453.700 us; speedup 1.0000x reference)
//
#include <hip/hip_runtime.h>
#include <hip/hip_fp16.h>

#define NB 8
#define CC 256
#define NN 2304
#define TK 32
#define QSZ ((size_t)NB * NN * CC)

typedef __attribute__((ext_vector_type(8))) _Float16 half8;
typedef __attribute__((ext_vector_type(4))) float f32x4;
typedef __attribute__((ext_vector_type(4))) unsigned short us4;

#define MFMAH(a, b, c) __builtin_amdgcn_mfma_f32_16x16x32_f16((a), (b), (c), 0, 0, 0)

__device__ __forceinline__ unsigned short f2h(float f) {
    union { _Float16 x; unsigned short u; } c;
    c.x = (_Float16)f;
    return c.u;
}
__device__ __forceinline__ unsigned short f2bf(float f) {
    unsigned int u = __float_as_uint(f);
    u = (u + 0x7fffu + ((u >> 16) & 1u)) >> 16;
    return (unsigned short)u;
}
__device__ __forceinline__ float bf2f(unsigned short h) {
    return __uint_as_float(((unsigned int)h) << 16);
}

// ---- fold output projection + BN into per-channel scale/bias ----
__global__ void prep_s2(const float* __restrict__ w_o, const float* __restrict__ b_o,
                        const float* __restrict__ gam, const float* __restrict__ bet,
                        const float* __restrict__ mea, const float* __restrict__ var,
                        float* __restrict__ s2b2) {
    int c = threadIdx.x;
    float inv = gam[c] * rsqrtf(var[c] + 1e-5f);
    s2b2[c]      = w_o[c] * inv;
    s2b2[CC + c] = b_o[c] * inv + bet[c] - mea[c] * inv;
}

// ---- transpose + project x -> Q, K fp16 (B,N,C); FUSED: also V^T (B,C,N) ----
__global__ __launch_bounds__(256) void prep_qk(
    const float* __restrict__ x,
    const float* __restrict__ w_t, const float* __restrict__ b_t,
    const float* __restrict__ w_p, const float* __restrict__ b_p,
    const float* __restrict__ w_g, const float* __restrict__ b_g,
    unsigned short* __restrict__ qf, unsigned short* __restrict__ kf,
    unsigned short* __restrict__ vt) {
    __shared__ float tile[64][65];
    int bid = blockIdx.x;
    int b  = bid / 144;
    int r  = bid % 144;
    int n0 = (r / 4) * 64;
    int c0 = (r % 4) * 64;
    int t  = threadIdx.x;
    int tx = t & 15, ty = t >> 4;

#pragma unroll
    for (int i = 0; i < 4; ++i) {
        int c = ty + i * 16;
        size_t xoff = (size_t)(b * CC + c0 + c) * NN + n0 + tx * 4;
        const float4 v = *(const float4*)&x[xoff];
        tile[c][tx * 4 + 0] = v.x;
        tile[c][tx * 4 + 1] = v.y;
        tile[c][tx * 4 + 2] = v.z;
        tile[c][tx * 4 + 3] = v.w;
        // fused V^T projection (same layout as x, no transpose needed)
        float wg = w_g[c0 + c], bg = b_g[c0 + c];
        us4 o;
        o[0] = f2h(v.x * wg + bg);
        o[1] = f2h(v.y * wg + bg);
        o[2] = f2h(v.z * wg + bg);
        o[3] = f2h(v.w * wg + bg);
        *(us4*)&vt[xoff] = o;
    }
    __syncthreads();
#pragma unroll
    for (int i = 0; i < 4; ++i) {
        int n = ty + i * 16;
        us4 qv, kv;
#pragma unroll
        for (int k = 0; k < 4; ++k) {
            int c = c0 + tx * 4 + k;
            float v = tile[tx * 4 + k][n];
            qv[k] = f2h(v * w_t[c] + b_t[c]);
            kv[k] = f2h(v * w_p[c] + b_p[c]);
        }
        size_t off = (size_t)(b * NN + n0 + n) * CC + c0 + tx * 4;
        *(us4*)&qf[off] = qv;
        *(us4*)&kf[off] = kv;
    }
}

// ---- flash attention: TK=32, swapped QK^T with permuted K staging (P in-register).
//      NO launch_bounds: default VGPR cap 128 >= ~104 demand (no spill), and no
//      min-waves constraint -> HW residency can reach 4 blocks/CU (LDS 37.4KB). ----
__global__ void attn(
    const unsigned short* __restrict__ qf, const unsigned short* __restrict__ kf,
    const unsigned short* __restrict__ vt,
    unsigned short* __restrict__ py, float2* __restrict__ pml,
    int keys_per) {
    __shared__ __align__(16) unsigned short kh_s[TK][264];  // K fp16, permuted rows
    __shared__ __align__(16) unsigned short vt_s[CC][40];   // V^T fp16

    // XCD-chunked swizzle
    int bid = (int)((blockIdx.x & 7) * (gridDim.x >> 3) + (blockIdx.x >> 3));
    int s  = bid / (NB * 36);
    int r  = bid % (NB * 36);
    int b  = r / 36;
    int n0 = (r % 36) * 64;
    int t  = threadIdx.x;
    int w  = t >> 6;
    int l  = t & 63;
    int g  = l >> 4;
    int ln = l & 15;
    int k0 = s * keys_per;

    // Q fragments: lane holds Q[n0+16w+ln][kb*32 + g*8 + j] (B-operand after swap)
    half8 qh[8];
    {
        size_t base = (size_t)(b * NN + n0 + w * 16 + ln) * CC + g * 8;
#pragma unroll
        for (int kb = 0; kb < 8; ++kb)
            qh[kb] = *(const half8*)&qf[base + kb * 32];
    }

    f32x4 y[16];
#pragma unroll
    for (int ct = 0; ct < 16; ++ct) y[ct] = (f32x4){0.f, 0.f, 0.f, 0.f};
    float m_run = -1e30f;   // per-lane: q-row = ln
    float l_run = 0.f;

    // register staging (next tile)
    half8 skh[4], svv[4];

    // K row permutation: kperm(r) = 8*((r&15)>>2) + 4*(r>>4) + (r&3)
#define KPERM(rr) (8 * (((rr) & 15) >> 2) + 4 * ((rr) >> 4) + ((rr) & 3))

    // load + store tile 0
#pragma unroll
    for (int i = 0; i < 4; ++i) {
        int u = i * 256 + t;
        int row = u >> 5, col = (u & 31) * 8;
        skh[i] = *(const half8*)&kf[(size_t)(b * NN + k0 + KPERM(row)) * CC + col];
        int c = u >> 2, mq = (u & 3) * 8;
        svv[i] = *(const half8*)&vt[(size_t)(b * CC + c) * NN + k0 + mq];
    }
#pragma unroll
    for (int i = 0; i < 4; ++i) {
        int u = i * 256 + t;
        int row = u >> 5, col = (u & 31) * 8;
        *(half8*)&kh_s[row][col] = skh[i];
        int c = u >> 2, mq = (u & 3) * 8;
        *(half8*)&vt_s[c][mq] = svv[i];
    }
    __syncthreads();

    int nkt = keys_per / TK;
    for (int kt = 0; kt < nkt; ++kt) {
        bool more = (kt + 1) < nkt;
        if (more) {   // issue next-tile loads; land under compute (T14)
            int m1 = k0 + (kt + 1) * TK;
#pragma unroll
            for (int i = 0; i < 4; ++i) {
                int u = i * 256 + t;
                int row = u >> 5, col = (u & 31) * 8;
                skh[i] = *(const half8*)&kf[(size_t)(b * NN + m1 + KPERM(row)) * CC + col];
                int c = u >> 2, mq = (u & 3) * 8;
                svv[i] = *(const half8*)&vt[(size_t)(b * CC + c) * NN + m1 + mq];
            }
        }

        // S^T = K Q^T (swapped); permuted staging => s0[reg]=S[key 8g+reg][q=ln],
        // s1[reg]=S[key 8g+4+reg][q=ln]
        f32x4 sa0 = (f32x4){0.f,0.f,0.f,0.f}, sb0 = sa0, sa1 = sa0, sb1 = sa0;
        __builtin_amdgcn_s_setprio(1);
#pragma unroll
        for (int k2 = 0; k2 < 4; ++k2) {
            int kA = k2 * 2, kB = k2 * 2 + 1;
            half8 bA0 = *(const half8*)&kh_s[ln][kA * 32 + g * 8];
            half8 bA1 = *(const half8*)&kh_s[16 + ln][kA * 32 + g * 8];
            half8 bB0 = *(const half8*)&kh_s[ln][kB * 32 + g * 8];
            half8 bB1 = *(const half8*)&kh_s[16 + ln][kB * 32 + g * 8];
            sa0 = MFMAH(bA0, qh[kA], sa0);
            sa1 = MFMAH(bA1, qh[kA], sa1);
            sb0 = MFMAH(bB0, qh[kB], sb0);
            sb1 = MFMAH(bB1, qh[kB], sb1);
        }
        __builtin_amdgcn_s_setprio(0);
        f32x4 s0 = sa0 + sb0;
        f32x4 s1 = sa1 + sb1;

        // row-softmax: q=ln lane-local -> 7 local fmax + 2 shfl
        float vmax = fmaxf(fmaxf(fmaxf(s0[0], s0[1]), fmaxf(s0[2], s0[3])),
                           fmaxf(fmaxf(s1[0], s1[1]), fmaxf(s1[2], s1[3])));
        vmax = fmaxf(vmax, __shfl_xor(vmax, 16));
        vmax = fmaxf(vmax, __shfl_xor(vmax, 32));
        // defer-max (THR=8)
        if (__any(vmax > m_run + 8.f)) {
            float mnew  = fmaxf(m_run, vmax);
            float alpha = __expf(m_run - mnew);
            m_run = mnew;
            l_run *= alpha;
            float aj[4];
#pragma unroll
            for (int j = 0; j < 4; ++j) aj[j] = __shfl(alpha, g * 4 + j);
#pragma unroll
            for (int ct = 0; ct < 16; ++ct) {
                y[ct][0] *= aj[0]; y[ct][1] *= aj[1];
                y[ct][2] *= aj[2]; y[ct][3] *= aj[3];
            }
        }
        // P in-register: pa[j] = P[q=ln][key 8g+j] — exactly the PV A-fragment
        half8 pa;
        float psum = 0.f;
#pragma unroll
        for (int j = 0; j < 4; ++j) {
            float p0 = __expf(s0[j] - m_run);
            float p1 = __expf(s1[j] - m_run);
            pa[j]     = (_Float16)p0;
            pa[4 + j] = (_Float16)p1;
            psum += p0 + p1;
        }
        psum += __shfl_xor(psum, 16);
        psum += __shfl_xor(psum, 32);
        l_run += psum;

        // PV (A = in-register P; B = V^T from LDS, keys unpermuted = 8g+j)
        __builtin_amdgcn_s_setprio(1);
#pragma unroll
        for (int ct = 0; ct < 16; ++ct) {
            half8 vb = *(const half8*)&vt_s[ct * 16 + ln][g * 8];
            y[ct] = MFMAH(pa, vb, y[ct]);
        }
        __builtin_amdgcn_s_setprio(0);

        if (more) {
            __syncthreads();   // all waves done reading current tiles
#pragma unroll
            for (int i = 0; i < 4; ++i) {
                int u = i * 256 + t;
                int row = u >> 5, col = (u & 31) * 8;
                *(half8*)&kh_s[row][col] = skh[i];
                int c = u >> 2, mq = (u & 3) * 8;
                *(half8*)&vt_s[c][mq] = svv[i];
            }
            __syncthreads();   // tiles ready
        }
    }
#undef KPERM

    // write unnormalized partial y (bf16) + per-row (m, l); (m,l) lives at q=ln
#pragma unroll
    for (int j = 0; j < 4; ++j) {
        int n = n0 + w * 16 + g * 4 + j;
        size_t rowb = ((size_t)(s * NB + b) * NN + n) * CC;
#pragma unroll
        for (int ct = 0; ct < 16; ++ct)
            py[rowb + ct * 16 + ln] = f2bf(y[ct][j]);
    }
    if (g == 0)
        pml[(size_t)(s * NB + b) * NN + n0 + w * 16 + ln] = make_float2(m_run, l_run);
}

// ---- combine splits + out-proj/BN/residual; out layout (B,C,N) ----
__global__ __launch_bounds__(256) void combine(
    const unsigned short* __restrict__ py, const float2* __restrict__ pml,
    const float* __restrict__ x, const float* __restrict__ s2b2,
    float* __restrict__ out, int S) {
    __shared__ float ptile[64][65];
    int bid = blockIdx.x;
    int b  = bid / 36;
    int n0 = (bid % 36) * 64;
    int t  = threadIdx.x;
    int w  = t >> 6;
    int l  = t & 63;
    int n  = n0 + l;

    float M = -1e30f;
    for (int s = 0; s < S; ++s)
        M = fmaxf(M, pml[(size_t)(s * NB + b) * NN + n].x);
    float L = 0.f;
    for (int s = 0; s < S; ++s) {
        float2 ml = pml[(size_t)(s * NB + b) * NN + n];
        L += ml.y * __expf(ml.x - M);
    }

    float acc[64];
#pragma unroll
    for (int a = 0; a < 64; ++a) acc[a] = 0.f;

    for (int s = 0; s < S; ++s) {
        float wgt = __expf(pml[(size_t)(s * NB + b) * NN + n].x - M);
#pragma unroll
        for (int cc = 0; cc < 4; ++cc) {
            __syncthreads();
#pragma unroll
            for (int i = 0; i < 4; ++i) {
                int u = i * 256 + t;
                int row = u >> 4, c4 = (u & 15) * 4;
                us4 v = *(const us4*)&py[((size_t)(s * NB + b) * NN + n0 + row) * CC + cc * 64 + c4];
                ptile[row][c4 + 0] = bf2f(v[0]);
                ptile[row][c4 + 1] = bf2f(v[1]);
                ptile[row][c4 + 2] = bf2f(v[2]);
                ptile[row][c4 + 3] = bf2f(v[3]);
            }
            __syncthreads();
#pragma unroll
            for (int i = 0; i < 16; ++i)
                acc[cc * 16 + i] += wgt * ptile[l][w * 16 + i];
        }
    }

    float invL = 1.f / L;
#pragma unroll
    for (int cc = 0; cc < 4; ++cc) {
#pragma unroll
        for (int i = 0; i < 16; ++i) {
            int c = cc * 64 + w * 16 + i;
            size_t idx = ((size_t)b * CC + c) * NN + n;
            out[idx] = acc[cc * 16 + i] * invL * s2b2[c] + s2b2[CC + c] + x[idx];
        }
    }
}

extern "C" void kernel_launch(void* const* d_in, const int* in_sizes, int n_in,
                              void* d_out, int out_size, void* d_ws, size_t ws_size,
                              hipStream_t stream) {
    const float* x   = (const float*)d_in[0];
    const float* w_g = (const float*)d_in[1];
    const float* b_g = (const float*)d_in[2];
    const float* w_t = (const float*)d_in[3];
    const float* b_t = (const float*)d_in[4];
    const float* w_p = (const float*)d_in[5];
    const float* b_p = (const float*)d_in[6];
    const float* w_o = (const float*)d_in[7];
    const float* b_o = (const float*)d_in[8];
    const float* gam = (const float*)d_in[9];
    const float* bet = (const float*)d_in[10];
    const float* mea = (const float*)d_in[11];
    const float* var = (const float*)d_in[12];
    float* out = (float*)d_out;

    unsigned short* qf = (unsigned short*)d_ws;
    unsigned short* kf = qf + QSZ;
    unsigned short* vt = kf + QSZ;
    float* s2b2 = (float*)(vt + QSZ);

    // S=4 proven best (R18: S=2 regressed via block-granularity imbalance)
    size_t base_b = 3 * QSZ * 2 + 2048;
    size_t per_b  = QSZ * 2 + (size_t)NB * NN * 8;
    int S = 1;
    if (base_b + 4 * per_b <= ws_size) S = 4;
    else if (base_b + 2 * per_b <= ws_size) S = 2;

    float2* pml = (float2*)((char*)d_ws + base_b);
    unsigned short* py = (unsigned short*)(pml + (size_t)S * NB * NN);

    prep_s2<<<1, 256, 0, stream>>>(w_o, b_o, gam, bet, mea, var, s2b2);
    prep_qk<<<NB * 36 * 4, 256, 0, stream>>>(x, w_t, b_t, w_p, b_p, w_g, b_g, qf, kf, vt);
    attn<<<NB * 36 * S, 256, 0, stream>>>(qf, kf, vt, py, pml, NN / S);
    combine<<<NB * 36, 256, 0, stream>>>(py, pml, x, s2b2, out, S);
}

// Round 26
// 126.571 us; speedup vs baseline: 3.5845x; 3.5845x over previous
//
#include <hip/hip_runtime.h>
#include <hip/hip_fp16.h>

#define NB 8
#define CC 256
#define NN 2304
#define TK 64
#define QSZ ((size_t)NB * NN * CC)

typedef __attribute__((ext_vector_type(8))) _Float16 half8;
typedef __attribute__((ext_vector_type(4))) float f32x4;
typedef __attribute__((ext_vector_type(4))) unsigned short us4;

#define MFMAH(a, b, c) __builtin_amdgcn_mfma_f32_16x16x32_f16((a), (b), (c), 0, 0, 0)

__device__ __forceinline__ unsigned short f2h(float f) {
    union { _Float16 x; unsigned short u; } c;
    c.x = (_Float16)f;
    return c.u;
}
__device__ __forceinline__ unsigned short f2bf(float f) {
    unsigned int u = __float_as_uint(f);
    u = (u + 0x7fffu + ((u >> 16) & 1u)) >> 16;
    return (unsigned short)u;
}
__device__ __forceinline__ float bf2f(unsigned short h) {
    return __uint_as_float(((unsigned int)h) << 16);
}

// ---- fold output projection + BN into per-channel scale/bias ----
__global__ void prep_s2(const float* __restrict__ w_o, const float* __restrict__ b_o,
                        const float* __restrict__ gam, const float* __restrict__ bet,
                        const float* __restrict__ mea, const float* __restrict__ var,
                        float* __restrict__ s2b2) {
    int c = threadIdx.x;
    float inv = gam[c] * rsqrtf(var[c] + 1e-5f);
    s2b2[c]      = w_o[c] * inv;
    s2b2[CC + c] = b_o[c] * inv + bet[c] - mea[c] * inv;
}

// ---- transpose + project x -> Q, K fp16 (B,N,C); FUSED: also V^T (B,C,N) ----
__global__ __launch_bounds__(256) void prep_qk(
    const float* __restrict__ x,
    const float* __restrict__ w_t, const float* __restrict__ b_t,
    const float* __restrict__ w_p, const float* __restrict__ b_p,
    const float* __restrict__ w_g, const float* __restrict__ b_g,
    unsigned short* __restrict__ qf, unsigned short* __restrict__ kf,
    unsigned short* __restrict__ vt) {
    __shared__ float tile[64][65];
    int bid = blockIdx.x;
    int b  = bid / 144;
    int r  = bid % 144;
    int n0 = (r / 4) * 64;
    int c0 = (r % 4) * 64;
    int t  = threadIdx.x;
    int tx = t & 15, ty = t >> 4;

#pragma unroll
    for (int i = 0; i < 4; ++i) {
        int c = ty + i * 16;
        size_t xoff = (size_t)(b * CC + c0 + c) * NN + n0 + tx * 4;
        const float4 v = *(const float4*)&x[xoff];
        tile[c][tx * 4 + 0] = v.x;
        tile[c][tx * 4 + 1] = v.y;
        tile[c][tx * 4 + 2] = v.z;
        tile[c][tx * 4 + 3] = v.w;
        // fused V^T projection (same layout as x, no transpose needed)
        float wg = w_g[c0 + c], bg = b_g[c0 + c];
        us4 o;
        o[0] = f2h(v.x * wg + bg);
        o[1] = f2h(v.y * wg + bg);
        o[2] = f2h(v.z * wg + bg);
        o[3] = f2h(v.w * wg + bg);
        *(us4*)&vt[xoff] = o;
    }
    __syncthreads();
#pragma unroll
    for (int i = 0; i < 4; ++i) {
        int n = ty + i * 16;
        us4 qv, kv;
#pragma unroll
        for (int k = 0; k < 4; ++k) {
            int c = c0 + tx * 4 + k;
            float v = tile[tx * 4 + k][n];
            qv[k] = f2h(v * w_t[c] + b_t[c]);
            kv[k] = f2h(v * w_p[c] + b_p[c]);
        }
        size_t off = (size_t)(b * NN + n0 + n) * CC + c0 + tx * 4;
        *(us4*)&qf[off] = qv;
        *(us4*)&kf[off] = kv;
    }
}

// ---- flash attention: TK=64, swapped QK^T with permuted K staging (P in-register),
//      shuffle-free common path: local-max defer check + epilogue l-reduction ----
__global__ __launch_bounds__(256, 2) void attn(
    const unsigned short* __restrict__ qf, const unsigned short* __restrict__ kf,
    const unsigned short* __restrict__ vt,
    unsigned short* __restrict__ py, float2* __restrict__ pml,
    int keys_per) {
    __shared__ __align__(16) unsigned short kh_s[TK][264];  // K fp16, permuted rows
    __shared__ __align__(16) unsigned short vt_s[CC][72];   // V^T fp16, keys 0..63

    // XCD-chunked swizzle
    int bid = (int)((blockIdx.x & 7) * (gridDim.x >> 3) + (blockIdx.x >> 3));
    int s  = bid / (NB * 36);
    int r  = bid % (NB * 36);
    int b  = r / 36;
    int n0 = (r % 36) * 64;
    int t  = threadIdx.x;
    int w  = t >> 6;
    int l  = t & 63;
    int g  = l >> 4;
    int ln = l & 15;
    int k0 = s * keys_per;

    // Q fragments: lane holds Q[n0+16w+ln][kb*32 + g*8 + j] (B-operand after swap)
    half8 qh[8];
    {
        size_t base = (size_t)(b * NN + n0 + w * 16 + ln) * CC + g * 8;
#pragma unroll
        for (int kb = 0; kb < 8; ++kb)
            qh[kb] = *(const half8*)&qf[base + kb * 32];
    }

    f32x4 y[16];
#pragma unroll
    for (int ct = 0; ct < 16; ++ct) y[ct] = (f32x4){0.f, 0.f, 0.f, 0.f};
    float m_run = -1e30f;   // row-wide max for q-row = ln (consistent across g)
    float l_run = 0.f;      // PER-LANE partial sum (reduced across g at epilogue)

    // register staging (next tile): 8 units K + 8 units V
    half8 skh[8], svv[8];

    // K row permutation within 64-row tile:
    // kperm(r) = (r&32) + 8*((r&15)>>2) + 4*((r>>4)&1) + (r&3)
    // => QK output (swapped): s0[reg]=key 8g+reg, s1=8g+4+reg, s2=32+8g+reg, s3=32+8g+4+reg
#define KPERM(rr) (((rr) & 32) + 8 * (((rr) & 15) >> 2) + 4 * (((rr) >> 4) & 1) + ((rr) & 3))

    // load + store tile 0
#pragma unroll
    for (int i = 0; i < 8; ++i) {
        int u = i * 256 + t;
        int row = u >> 5, col = (u & 31) * 8;
        skh[i] = *(const half8*)&kf[(size_t)(b * NN + k0 + KPERM(row)) * CC + col];
        int c = u >> 3, mq = (u & 7) * 8;
        svv[i] = *(const half8*)&vt[(size_t)(b * CC + c) * NN + k0 + mq];
    }
#pragma unroll
    for (int i = 0; i < 8; ++i) {
        int u = i * 256 + t;
        int row = u >> 5, col = (u & 31) * 8;
        *(half8*)&kh_s[row][col] = skh[i];
        int c = u >> 3, mq = (u & 7) * 8;
        *(half8*)&vt_s[c][mq] = svv[i];
    }
    __syncthreads();

    int nkt = keys_per / TK;
    for (int kt = 0; kt < nkt; ++kt) {
        bool more = (kt + 1) < nkt;
        if (more) {   // issue next-tile loads; land under QK+softmax+PV (T14)
            int m1 = k0 + (kt + 1) * TK;
#pragma unroll
            for (int i = 0; i < 8; ++i) {
                int u = i * 256 + t;
                int row = u >> 5, col = (u & 31) * 8;
                skh[i] = *(const half8*)&kf[(size_t)(b * NN + m1 + KPERM(row)) * CC + col];
                int c = u >> 3, mq = (u & 7) * 8;
                svv[i] = *(const half8*)&vt[(size_t)(b * CC + c) * NN + m1 + mq];
            }
        }

        // S^T = K Q^T over 4 key-groups, 8 indep chains
        f32x4 sA0 = (f32x4){0.f,0.f,0.f,0.f}, sA1 = sA0, sA2 = sA0, sA3 = sA0;
        f32x4 sB0 = sA0, sB1 = sA0, sB2 = sA0, sB3 = sA0;
        __builtin_amdgcn_s_setprio(1);
#pragma unroll
        for (int k2 = 0; k2 < 4; ++k2) {
            int kA = k2 * 2, kB = k2 * 2 + 1;
            half8 a0 = *(const half8*)&kh_s[ln][kA * 32 + g * 8];
            half8 a1 = *(const half8*)&kh_s[16 + ln][kA * 32 + g * 8];
            half8 a2 = *(const half8*)&kh_s[32 + ln][kA * 32 + g * 8];
            half8 a3 = *(const half8*)&kh_s[48 + ln][kA * 32 + g * 8];
            sA0 = MFMAH(a0, qh[kA], sA0);
            sA1 = MFMAH(a1, qh[kA], sA1);
            sA2 = MFMAH(a2, qh[kA], sA2);
            sA3 = MFMAH(a3, qh[kA], sA3);
            half8 b0 = *(const half8*)&kh_s[ln][kB * 32 + g * 8];
            half8 b1 = *(const half8*)&kh_s[16 + ln][kB * 32 + g * 8];
            half8 b2 = *(const half8*)&kh_s[32 + ln][kB * 32 + g * 8];
            half8 b3 = *(const half8*)&kh_s[48 + ln][kB * 32 + g * 8];
            sB0 = MFMAH(b0, qh[kB], sB0);
            sB1 = MFMAH(b1, qh[kB], sB1);
            sB2 = MFMAH(b2, qh[kB], sB2);
            sB3 = MFMAH(b3, qh[kB], sB3);
        }
        __builtin_amdgcn_s_setprio(0);
        f32x4 s0 = sA0 + sB0;   // keys 8g+reg
        f32x4 s1 = sA1 + sB1;   // keys 8g+4+reg
        f32x4 s2 = sA2 + sB2;   // keys 32+8g+reg
        f32x4 s3 = sA3 + sB3;   // keys 32+8g+4+reg

        // LOCAL max only (no shuffles in common path)
        float v01 = fmaxf(fmaxf(fmaxf(s0[0], s0[1]), fmaxf(s0[2], s0[3])),
                          fmaxf(fmaxf(s1[0], s1[1]), fmaxf(s1[2], s1[3])));
        float v23 = fmaxf(fmaxf(fmaxf(s2[0], s2[1]), fmaxf(s2[2], s2[3])),
                          fmaxf(fmaxf(s3[0], s3[1]), fmaxf(s3[2], s3[3])));
        float lmax = fmaxf(v01, v23);
        // defer-max: row max > m+8 iff some lane's local max is (max of maxes)
        if (__any(lmax > m_run + 8.f)) {
            float vmax = fmaxf(lmax, __shfl_xor(lmax, 16));   // full row reduce, rare
            vmax = fmaxf(vmax, __shfl_xor(vmax, 32));
            float mnew  = fmaxf(m_run, vmax);
            float alpha = __expf(m_run - mnew);
            m_run = mnew;
            l_run *= alpha;        // per-lane partial scaled by row-wide alpha
            float aj[4];
#pragma unroll
            for (int j = 0; j < 4; ++j) aj[j] = __shfl(alpha, g * 4 + j);
#pragma unroll
            for (int ct = 0; ct < 16; ++ct) {
                y[ct][0] *= aj[0]; y[ct][1] *= aj[1];
                y[ct][2] *= aj[2]; y[ct][3] *= aj[3];
            }
        }
        // P in-register: pa0 = keys {8g+j}, pa1 = keys {32+8g+j} — PV A-fragments
        half8 pa0, pa1;
        float psum = 0.f;
#pragma unroll
        for (int j = 0; j < 4; ++j) {
            float p0 = __expf(s0[j] - m_run);
            float p1 = __expf(s1[j] - m_run);
            float p2 = __expf(s2[j] - m_run);
            float p3 = __expf(s3[j] - m_run);
            pa0[j]     = (_Float16)p0;
            pa0[4 + j] = (_Float16)p1;
            pa1[j]     = (_Float16)p2;
            pa1[4 + j] = (_Float16)p3;
            psum += (p0 + p1) + (p2 + p3);
        }
        l_run += psum;   // per-lane partial; cross-lane reduce deferred to epilogue

        // PV: 2 MFMA per out-tile
        __builtin_amdgcn_s_setprio(1);
#pragma unroll
        for (int ct = 0; ct < 16; ++ct) {
            half8 vb0 = *(const half8*)&vt_s[ct * 16 + ln][g * 8];
            half8 vb1 = *(const half8*)&vt_s[ct * 16 + ln][32 + g * 8];
            y[ct] = MFMAH(pa1, vb1, MFMAH(pa0, vb0, y[ct]));
        }
        __builtin_amdgcn_s_setprio(0);

        if (more) {
            __syncthreads();
#pragma unroll
            for (int i = 0; i < 8; ++i) {
                int u = i * 256 + t;
                int row = u >> 5, col = (u & 31) * 8;
                *(half8*)&kh_s[row][col] = skh[i];
                int c = u >> 3, mq = (u & 7) * 8;
                *(half8*)&vt_s[c][mq] = svv[i];
            }
            __syncthreads();
        }
    }
#undef KPERM

    // epilogue: reduce l across g-groups (deferred), then write partials
    l_run += __shfl_xor(l_run, 16);
    l_run += __shfl_xor(l_run, 32);
#pragma unroll
    for (int j = 0; j < 4; ++j) {
        int n = n0 + w * 16 + g * 4 + j;
        size_t rowb = ((size_t)(s * NB + b) * NN + n) * CC;
#pragma unroll
        for (int ct = 0; ct < 16; ++ct)
            py[rowb + ct * 16 + ln] = f2bf(y[ct][j]);
    }
    if (g == 0)
        pml[(size_t)(s * NB + b) * NN + n0 + w * 16 + ln] = make_float2(m_run, l_run);
}

// ---- combine splits + out-proj/BN/residual; out layout (B,C,N) ----
__global__ __launch_bounds__(256) void combine(
    const unsigned short* __restrict__ py, const float2* __restrict__ pml,
    const float* __restrict__ x, const float* __restrict__ s2b2,
    float* __restrict__ out, int S) {
    __shared__ float ptile[64][65];
    int bid = blockIdx.x;
    int b  = bid / 36;
    int n0 = (bid % 36) * 64;
    int t  = threadIdx.x;
    int w  = t >> 6;
    int l  = t & 63;
    int n  = n0 + l;

    float M = -1e30f;
    for (int s = 0; s < S; ++s)
        M = fmaxf(M, pml[(size_t)(s * NB + b) * NN + n].x);
    float L = 0.f;
    for (int s = 0; s < S; ++s) {
        float2 ml = pml[(size_t)(s * NB + b) * NN + n];
        L += ml.y * __expf(ml.x - M);
    }

    float acc[64];
#pragma unroll
    for (int a = 0; a < 64; ++a) acc[a] = 0.f;

    for (int s = 0; s < S; ++s) {
        float wgt = __expf(pml[(size_t)(s * NB + b) * NN + n].x - M);
#pragma unroll
        for (int cc = 0; cc < 4; ++cc) {
            __syncthreads();
#pragma unroll
            for (int i = 0; i < 4; ++i) {
                int u = i * 256 + t;
                int row = u >> 4, c4 = (u & 15) * 4;
                us4 v = *(const us4*)&py[((size_t)(s * NB + b) * NN + n0 + row) * CC + cc * 64 + c4];
                ptile[row][c4 + 0] = bf2f(v[0]);
                ptile[row][c4 + 1] = bf2f(v[1]);
                ptile[row][c4 + 2] = bf2f(v[2]);
                ptile[row][c4 + 3] = bf2f(v[3]);
            }
            __syncthreads();
#pragma unroll
            for (int i = 0; i < 16; ++i)
                acc[cc * 16 + i] += wgt * ptile[l][w * 16 + i];
        }
    }

    float invL = 1.f / L;
#pragma unroll
    for (int cc = 0; cc < 4; ++cc) {
#pragma unroll
        for (int i = 0; i < 16; ++i) {
            int c = cc * 64 + w * 16 + i;
            size_t idx = ((size_t)b * CC + c) * NN + n;
            out[idx] = acc[cc * 16 + i] * invL * s2b2[c] + s2b2[CC + c] + x[idx];
        }
    }
}

extern "C" void kernel_launch(void* const* d_in, const int* in_sizes, int n_in,
                              void* d_out, int out_size, void* d_ws, size_t ws_size,
                              hipStream_t stream) {
    const float* x   = (const float*)d_in[0];
    const float* w_g = (const float*)d_in[1];
    const float* b_g = (const float*)d_in[2];
    const float* w_t = (const float*)d_in[3];
    const float* b_t = (const float*)d_in[4];
    const float* w_p = (const float*)d_in[5];
    const float* b_p = (const float*)d_in[6];
    const float* w_o = (const float*)d_in[7];
    const float* b_o = (const float*)d_in[8];
    const float* gam = (const float*)d_in[9];
    const float* bet = (const float*)d_in[10];
    const float* mea = (const float*)d_in[11];
    const float* var = (const float*)d_in[12];
    float* out = (float*)d_out;

    unsigned short* qf = (unsigned short*)d_ws;
    unsigned short* kf = qf + QSZ;
    unsigned short* vt = kf + QSZ;
    float* s2b2 = (float*)(vt + QSZ);

    // S=4 proven best (R18: S=2 regressed via block-granularity imbalance)
    size_t base_b = 3 * QSZ * 2 + 2048;
    size_t per_b  = QSZ * 2 + (size_t)NB * NN * 8;
    int S = 1;
    if (base_b + 4 * per_b <= ws_size) S = 4;
    else if (base_b + 2 * per_b <= ws_size) S = 2;

    float2* pml = (float2*)((char*)d_ws + base_b);
    unsigned short* py = (unsigned short*)(pml + (size_t)S * NB * NN);

    prep_s2<<<1, 256, 0, stream>>>(w_o, b_o, gam, bet, mea, var, s2b2);
    prep_qk<<<NB * 36 * 4, 256, 0, stream>>>(x, w_t, b_t, w_p, b_p, w_g, b_g, qf, kf, vt);
    attn<<<NB * 36 * S, 256, 0, stream>>>(qf, kf, vt, py, pml, NN / S);
    combine<<<NB * 36, 256, 0, stream>>>(py, pml, x, s2b2, out, S);
}